// Round 5
// baseline (712.821 us; speedup 1.0000x reference)
//
#include <hip/hip_runtime.h>
#include <hip/hip_bf16.h>

#define DEVI __device__ __forceinline__

typedef short bf16x8 __attribute__((ext_vector_type(8)));
typedef float f32x4  __attribute__((ext_vector_type(4)));

// Problem constants (B=32, H=W=56, C=256, wh=ww=7, shift=3, heads=8, hd=32)
constexpr int MROWS = 100352;            // 32 * 64 * 49 window-order rows

// window-order row -> flat token index (b*3136 + h*56 + w).
DEVI int win_row_to_token(int r) {
  int b   = r / 3136;
  int rem = r - b * 3136;
  int wi  = rem / 49;
  int t   = rem - wi * 49;
  int nwh = wi >> 3, nww = wi & 7;
  int th = t / 7, tw = t - th * 7;
  int h = nwh * 7 + th + 3; if (h >= 56) h -= 56;
  int w = nww * 7 + tw + 3; if (w >= 56) w -= 56;
  return b * 3136 + h * 56 + w;
}

DEVI unsigned short f2bf(float f) {
  __hip_bfloat16 h = __float2bfloat16(f);
  return __builtin_bit_cast(unsigned short, h);
}

// ---------------- fp32 -> bf16 weight convert ----------------
__global__ void cvt_kernel(const float* __restrict__ in, __hip_bfloat16* __restrict__ out, int n) {
  int i = blockIdx.x * 256 + threadIdx.x;
  if (i < n) out[i] = __float2bfloat16(in[i]);
}

// ---------------- LayerNorm (one wave per token row, C=256) ----------------
template<bool WIN>
__global__ __launch_bounds__(256) void ln_kernel(
    const float* __restrict__ xin, const float* __restrict__ g,
    const float* __restrict__ b, __hip_bfloat16* __restrict__ outb)
{
  int r = blockIdx.x * 4 + (threadIdx.x >> 6);
  int l = threadIdx.x & 63;
  int tok = WIN ? win_row_to_token(r) : r;
  float4 xv = *(const float4*)&xin[(size_t)tok * 256 + l * 4];
  float s = xv.x + xv.y + xv.z + xv.w;
  float q = xv.x * xv.x + xv.y * xv.y + xv.z * xv.z + xv.w * xv.w;
  #pragma unroll
  for (int off = 32; off; off >>= 1) { s += __shfl_xor(s, off); q += __shfl_xor(q, off); }
  float mu = s * (1.0f / 256.0f);
  float var = q * (1.0f / 256.0f) - mu * mu;
  float rs = rsqrtf(var + 1e-5f);
  float4 gv = *(const float4*)&g[l * 4];
  float4 bv = *(const float4*)&b[l * 4];
  ushort4 st;
  st.x = f2bf((xv.x - mu) * rs * gv.x + bv.x);
  st.y = f2bf((xv.y - mu) * rs * gv.y + bv.y);
  st.z = f2bf((xv.z - mu) * rs * gv.z + bv.z);
  st.w = f2bf((xv.w - mu) * rs * gv.w + bv.w);
  *(ushort4*)&outb[(size_t)r * 256 + l * 4] = st;
}

enum { EPI_QKV = 0, EPI_PROJ = 1, EPI_MLP1 = 2, EPI_MLP2 = 3 };

// ---------------- strip GEMM: B-frags in VGPRs, A streamed through LDS -----------
// 256 blocks (1/CU), 512 thr = 8 waves (4 wave-rows x 2 wave-cols), wave tile 64x64,
// block tile 256x128. A streamed in 32KB BK=64 chunks through a 3-deep LDS ring
// (global_load_lds w=16, source-side XOR pre-swizzle, read-side XOR).
// Per chunk: issue(next -> ring[np]); vmcnt(4); s_barrier; compute(ring[p]).
// Single barrier is race-free with 3 buffers: issue(i+2)'s target was last read at
// chunk i-1, and barrier(i) orders all waves past compute(i-1) before any wave
// reaches body i+1's issue. vmcnt(4) (self-certify own staging) precedes barrier.
// KTOT=256: whole B-panel (128 cols) resident in 128 VGPRs for the entire strip.
// KTOT=1024 (MLP2): B-frags reloaded per (nt,kb) quarter; acc persists across kb.
template<int EPI, int KTOT>
__global__ __launch_bounds__(512, 1) void strip_gemm(
    const __hip_bfloat16* __restrict__ A,
    const __hip_bfloat16* __restrict__ Bw,
    int ntiles,                        // N/128
    const float* __restrict__ bias,
    const float* __restrict__ xres,    // PROJ: original x (token order)
    float* __restrict__ outf,          // PROJ/MLP2: d_out
    __hip_bfloat16* __restrict__ outb) // QKV/MLP1
{
  constexpr int NKB = KTOT / 256;
  __shared__ __align__(16) __hip_bfloat16 Al[3][256 * 64];   // 3 x 32KB ring

  const int tid = threadIdx.x;
  const int w = tid >> 6, l = tid & 63;
  const int wr = w >> 1, wc = w & 1;          // 4 wave-rows, 2 wave-cols
  const int g = l >> 4, lm = l & 15;

  const int b   = blockIdx.x;
  const int xcd = b & 7;
  const int cu  = b >> 3;                     // 0..31
  const int T   = 49 * ntiles;                // tiles per XCD chunk (49 mt x ntiles)
  const int t0  = (cu * T) >> 5;
  const int t1  = ((cu + 1) * T) >> 5;
  const int nquads = (t1 - t0) * NKB;

  // stage one 256x64 A-chunk into ring buffer `buf`.
  // LDS 16B-unit U = row*8 + i holds global unit row*8 + (i ^ (row&7)).
  auto issue = [&](int mt, int koff, int buf) {
    const __hip_bfloat16* Ab = A + (size_t)mt * 256 * KTOT + koff;
    #pragma unroll
    for (int j = 0; j < 4; ++j) {
      int row = j * 64 + w * 8 + (l >> 3);
      int u = (l & 7) ^ (row & 7);
      __builtin_amdgcn_global_load_lds(
          (const __attribute__((address_space(1))) void*)((const char*)(Ab + (size_t)row * KTOT) + u * 16),
          (__attribute__((address_space(3))) void*)(&Al[buf][j * 4096 + w * 512]),
          16, 0, 0);
    }
  };

  bf16x8 Bf[4][8];                 // 4 col-frags x 8 k-frags resident (128 VGPR)
  f32x4  acc[4][4];
  int cur_key = -1;
  int p = 0;

  issue(xcd * 49 + (t0 - (t0 / 49) * 49), 0, 0);

  for (int qd = 0; qd < nquads; ++qd) {
    int tt = t0 + qd / NKB;
    int kb = qd - (qd / NKB) * NKB;
    int nt = tt / 49;
    int mt = xcd * 49 + (tt - nt * 49);

    int key = nt * NKB + kb;
    if (key != cur_key) {            // B-frag (re)load: L2-hot, no LDS touch
      #pragma unroll
      for (int ni = 0; ni < 4; ++ni)
        #pragma unroll
        for (int kf = 0; kf < 8; ++kf)
          Bf[ni][kf] = *(const bf16x8*)&Bw[
              (size_t)(nt * 128 + wc * 64 + ni * 16 + lm) * KTOT + kb * 256 + kf * 32 + g * 8];
      cur_key = key;
    }
    if (kb == 0) {
      #pragma unroll
      for (int mi = 0; mi < 4; ++mi)
        #pragma unroll
        for (int ni = 0; ni < 4; ++ni)
          acc[mi][ni] = f32x4{0.f, 0.f, 0.f, 0.f};
    }

    #pragma unroll
    for (int c = 0; c < 4; ++c) {    // compile-time c: Bf indexing stays static
      int np = (p == 2) ? 0 : p + 1;
      bool last = (qd == nquads - 1) && (c == 3);
      if (!last) {
        int qn = (c < 3) ? qd : qd + 1;
        int cn = (c < 3) ? c + 1 : 0;
        int tn  = t0 + qn / NKB;
        int kbn = qn - (qn / NKB) * NKB;
        int ntn = tn / 49;
        int mtn = xcd * 49 + (tn - ntn * 49);
        issue(mtn, kbn * 256 + cn * 64, np);
        asm volatile("s_waitcnt vmcnt(4)" ::: "memory");
      } else {
        asm volatile("s_waitcnt vmcnt(0)" ::: "memory");
      }
      __builtin_amdgcn_s_barrier();
      asm volatile("" ::: "memory");

      #pragma unroll
      for (int kk = 0; kk < 2; ++kk) {
        bf16x8 af[4];
        #pragma unroll
        for (int mi = 0; mi < 4; ++mi) {
          int r = wr * 64 + mi * 16 + lm;
          int u = (kk * 4 + g) ^ (r & 7);
          af[mi] = *(const bf16x8*)&Al[p][r * 64 + u * 8];
        }
        #pragma unroll
        for (int mi = 0; mi < 4; ++mi)
          #pragma unroll
          for (int ni = 0; ni < 4; ++ni)
            acc[mi][ni] = __builtin_amdgcn_mfma_f32_16x16x32_bf16(
                af[mi], Bf[ni][c * 2 + kk], acc[mi][ni], 0, 0, 0);
      }
      asm volatile("" ::: "memory");
      p = np;
    }

    if (kb == NKB - 1) {
      // ---- tile epilogue ----
      #pragma unroll
      for (int mi = 0; mi < 4; ++mi)
        #pragma unroll
        for (int j = 0; j < 4; ++j) {
          int grow = mt * 256 + wr * 64 + mi * 16 + g * 4 + j;
          int orow = grow;
          if (EPI == EPI_PROJ) orow = win_row_to_token(grow);
          #pragma unroll
          for (int ni = 0; ni < 4; ++ni) {
            int gcol = nt * 128 + wc * 64 + ni * 16 + lm;
            float v = acc[mi][ni][j] + bias[gcol];
            if (EPI == EPI_QKV) {
              outb[(size_t)grow * 768 + gcol] = __float2bfloat16(v);
            } else if (EPI == EPI_PROJ) {
              size_t o = (size_t)orow * 256 + gcol;
              outf[o] = xres[o] + v;
            } else if (EPI == EPI_MLP1) {
              float ge = 0.5f * v * (1.0f + erff(v * 0.70710678118654752f));
              outb[(size_t)grow * 1024 + gcol] = __float2bfloat16(ge);
            } else { // MLP2
              size_t o = (size_t)grow * 256 + gcol;
              outf[o] += v;
            }
          }
        }
    }
  }
}

// ---------------- Sadd precompute: bias+mask in MFMA frag layout ----------------
__global__ __launch_bounds__(256) void bias_prep_kernel(
    const float* __restrict__ bt, float* __restrict__ Sadd)
{
  int blk = blockIdx.x;            // class*8 + h
  int cls = blk >> 3, h = blk & 7;
  int re = cls >> 1, ce = cls & 1;
  int lane = threadIdx.x & 63, fs = threadIdx.x >> 6;
  int g = lane >> 4, lm = lane & 15;
  #pragma unroll
  for (int i = 0; i < 4; ++i) {
    int f = fs * 4 + i;
    int mi = f >> 2, ni = f & 3;
    int key = ni * 16 + lm;
    f32x4 v;
    #pragma unroll
    for (int j = 0; j < 4; ++j) {
      int q = mi * 16 + g * 4 + j;
      float val;
      if (key >= 49) {
        val = -1e30f;
      } else {
        int qq = q > 48 ? 48 : q;
        int qh = qq / 7, qw = qq - qh * 7;
        int kh = key / 7, kw = key - kh * 7;
        int rpi = (qh - kh + 6) * 13 + (qw - kw + 6);
        val = bt[rpi * 8 + h];
        int rq = (re ? (qh < 4 ? 1 : 2) : 0) * 3 + (ce ? (qw < 4 ? 1 : 2) : 0);
        int rk = (re ? (kh < 4 ? 1 : 2) : 0) * 3 + (ce ? (kw < 4 ? 1 : 2) : 0);
        if (rq != rk) val -= 100.0f;
      }
      v[j] = val;
    }
    ((f32x4*)Sadd)[(blk * 16 + f) * 64 + lane] = v;
  }
}

// ---------------- MFMA attention: block = (window, 4 heads), wave = head ----------
__global__ __launch_bounds__(256) void attn_mfma_kernel(
    const __hip_bfloat16* __restrict__ qkv,
    const float* __restrict__ Sadd,
    __hip_bfloat16* __restrict__ attn_out)
{
  __shared__ __align__(16) __hip_bfloat16 Pl[4][64 * 72];
  int blk = blockIdx.x;
  int win = blk >> 1, half = blk & 1;
  int w = threadIdx.x >> 6, l = threadIdx.x & 63;
  int head = half * 4 + w;
  int g = l >> 4, lm = l & 15;
  int wi = win & 63;
  int cls = (((wi >> 3) == 7) ? 2 : 0) | (((wi & 7) == 7) ? 1 : 0);
  const __hip_bfloat16* base = qkv + (size_t)win * 49 * 768 + head * 32;

  bf16x8 aQ[4], bK[4];
  #pragma unroll
  for (int mi = 0; mi < 4; ++mi) {
    int q = mi * 16 + lm; if (q > 48) q = 48;
    aQ[mi] = *(const bf16x8*)(base + q * 768 + g * 8);
  }
  #pragma unroll
  for (int ni = 0; ni < 4; ++ni) {
    int k = ni * 16 + lm; if (k > 48) k = 48;
    bK[ni] = *(const bf16x8*)(base + 256 + k * 768 + g * 8);
  }
  f32x4 acc[4][4] = {};
  #pragma unroll
  for (int mi = 0; mi < 4; ++mi)
    #pragma unroll
    for (int ni = 0; ni < 4; ++ni)
      acc[mi][ni] = __builtin_amdgcn_mfma_f32_16x16x32_bf16(aQ[mi], bK[ni], acc[mi][ni], 0, 0, 0);

  const float scale = 0.17677669529663687f;
  const f32x4* Sb = (const f32x4*)Sadd + (size_t)(cls * 8 + head) * 16 * 64 + l;

  f32x4 rsum[4];
  __hip_bfloat16* P = Pl[w];
  #pragma unroll
  for (int mi = 0; mi < 4; ++mi) {
    #pragma unroll
    for (int ni = 0; ni < 4; ++ni) {
      f32x4 sv = Sb[(mi * 4 + ni) * 64];
      #pragma unroll
      for (int j = 0; j < 4; ++j) acc[mi][ni][j] = acc[mi][ni][j] * scale + sv[j];
    }
    f32x4 mx = acc[mi][0];
    #pragma unroll
    for (int ni = 1; ni < 4; ++ni)
      #pragma unroll
      for (int j = 0; j < 4; ++j) mx[j] = fmaxf(mx[j], acc[mi][ni][j]);
    #pragma unroll
    for (int msk = 1; msk < 16; msk <<= 1)
      #pragma unroll
      for (int j = 0; j < 4; ++j) mx[j] = fmaxf(mx[j], __shfl_xor(mx[j], msk));
    f32x4 sm = {};
    #pragma unroll
    for (int ni = 0; ni < 4; ++ni)
      #pragma unroll
      for (int j = 0; j < 4; ++j) {
        float e = __expf(acc[mi][ni][j] - mx[j]);
        acc[mi][ni][j] = e;
        sm[j] += e;
      }
    #pragma unroll
    for (int msk = 1; msk < 16; msk <<= 1)
      #pragma unroll
      for (int j = 0; j < 4; ++j) sm[j] += __shfl_xor(sm[j], msk);
    rsum[mi] = sm;
    #pragma unroll
    for (int ni = 0; ni < 4; ++ni)
      #pragma unroll
      for (int j = 0; j < 4; ++j) {
        int q = mi * 16 + g * 4 + j;
        int key = ni * 16 + lm;
        P[q * 72 + key] = __float2bfloat16(acc[mi][ni][j]);
      }
  }

  bf16x8 bV[2][2];
  #pragma unroll
  for (int s = 0; s < 2; ++s)
    #pragma unroll
    for (int n2 = 0; n2 < 2; ++n2) {
      bf16x8 vv;
      #pragma unroll
      for (int e = 0; e < 8; ++e) {
        int key = s * 32 + g * 8 + e; if (key > 48) key = 48;
        vv[e] = __builtin_bit_cast(short, base[512 + key * 768 + n2 * 16 + lm]);
      }
      bV[s][n2] = vv;
    }

  f32x4 o[4][2] = {};
  #pragma unroll
  for (int s = 0; s < 2; ++s)
    #pragma unroll
    for (int mi2 = 0; mi2 < 4; ++mi2) {
      bf16x8 aP = *(const bf16x8*)&P[(mi2 * 16 + lm) * 72 + s * 32 + g * 8];
      #pragma unroll
      for (int n2 = 0; n2 < 2; ++n2)
        o[mi2][n2] = __builtin_amdgcn_mfma_f32_16x16x32_bf16(aP, bV[s][n2], o[mi2][n2], 0, 0, 0);
    }

  #pragma unroll
  for (int mi2 = 0; mi2 < 4; ++mi2) {
    f32x4 li;
    #pragma unroll
    for (int j = 0; j < 4; ++j) li[j] = 1.0f / rsum[mi2][j];
    #pragma unroll
    for (int n2 = 0; n2 < 2; ++n2)
      #pragma unroll
      for (int j = 0; j < 4; ++j) {
        int q = mi2 * 16 + g * 4 + j;
        if (q < 49)
          attn_out[((size_t)win * 49 + q) * 256 + head * 32 + n2 * 16 + lm] =
              __float2bfloat16(o[mi2][n2][j] * li[j]);
      }
  }
}

// ---------------- host launch ----------------
extern "C" void kernel_launch(void* const* d_in, const int* in_sizes, int n_in,
                              void* d_out, int out_size, void* d_ws, size_t ws_size,
                              hipStream_t stream) {
  const float* x          = (const float*)d_in[0];
  const float* g1         = (const float*)d_in[1];
  const float* b1         = (const float*)d_in[2];
  const float* qkv_w      = (const float*)d_in[3];
  const float* qkv_b      = (const float*)d_in[4];
  const float* bias_table = (const float*)d_in[5];
  const float* proj_w     = (const float*)d_in[6];
  const float* proj_b     = (const float*)d_in[7];
  const float* g2         = (const float*)d_in[8];
  const float* b2         = (const float*)d_in[9];
  const float* w1         = (const float*)d_in[10];
  const float* bm1        = (const float*)d_in[11];
  const float* w2         = (const float*)d_in[12];
  const float* bm2        = (const float*)d_in[13];
  float* out = (float*)d_out;

  char* ws = (char*)d_ws;
  __hip_bfloat16* A_ln   = (__hip_bfloat16*)(ws);
  __hip_bfloat16* qkvb   = (__hip_bfloat16*)(ws + 51380224);
  __hip_bfloat16* attn_o = (__hip_bfloat16*)(ws + 205520896);
  __hip_bfloat16* hidden = qkvb;
  __hip_bfloat16* qkv_wb  = (__hip_bfloat16*)(ws + 256901120);
  __hip_bfloat16* proj_wb = qkv_wb + 196608;
  __hip_bfloat16* w1b     = proj_wb + 65536;
  __hip_bfloat16* w2b     = w1b + 262144;
  float* Sadd = (float*)(ws + 258473984);

  cvt_kernel<<<(196608 + 255) / 256, 256, 0, stream>>>(qkv_w, qkv_wb, 196608);
  cvt_kernel<<<(65536  + 255) / 256, 256, 0, stream>>>(proj_w, proj_wb, 65536);
  cvt_kernel<<<(262144 + 255) / 256, 256, 0, stream>>>(w1, w1b, 262144);
  cvt_kernel<<<(262144 + 255) / 256, 256, 0, stream>>>(w2, w2b, 262144);
  bias_prep_kernel<<<32, 256, 0, stream>>>(bias_table, Sadd);

  ln_kernel<true><<<MROWS / 4, 256, 0, stream>>>(x, g1, b1, A_ln);

  strip_gemm<EPI_QKV, 256><<<256, 512, 0, stream>>>(
      A_ln, qkv_wb, 6, qkv_b, nullptr, nullptr, qkvb);

  attn_mfma_kernel<<<4096, 256, 0, stream>>>(qkvb, Sadd, attn_o);

  strip_gemm<EPI_PROJ, 256><<<256, 512, 0, stream>>>(
      attn_o, proj_wb, 2, proj_b, x, out, nullptr);

  ln_kernel<false><<<MROWS / 4, 256, 0, stream>>>(out, g2, b2, A_ln);

  strip_gemm<EPI_MLP1, 256><<<256, 512, 0, stream>>>(
      A_ln, w1b, 8, bm1, nullptr, nullptr, hidden);

  strip_gemm<EPI_MLP2, 1024><<<256, 512, 0, stream>>>(
      hidden, w2b, 2, bm2, nullptr, out, nullptr);
}

// Round 6
// 572.187 us; speedup vs baseline: 1.2458x; 1.2458x over previous
//
#include <hip/hip_runtime.h>
#include <hip/hip_bf16.h>

#define DEVI __device__ __forceinline__

typedef short bf16x8 __attribute__((ext_vector_type(8)));
typedef float f32x4  __attribute__((ext_vector_type(4)));

// Problem constants (B=32, H=W=56, C=256, wh=ww=7, shift=3, heads=8, hd=32)
constexpr int MROWS = 100352;            // 32 * 64 * 49 window-order rows
constexpr int BM = 128, BN = 128, BK = 64;

// window-order row -> flat token index (b*3136 + h*56 + w).
DEVI int win_row_to_token(int r) {
  int b   = r / 3136;
  int rem = r - b * 3136;
  int wi  = rem / 49;
  int t   = rem - wi * 49;
  int nwh = wi >> 3, nww = wi & 7;
  int th = t / 7, tw = t - th * 7;
  int h = nwh * 7 + th + 3; if (h >= 56) h -= 56;
  int w = nww * 7 + tw + 3; if (w >= 56) w -= 56;
  return b * 3136 + h * 56 + w;
}

DEVI unsigned short f2bf(float f) {
  __hip_bfloat16 h = __float2bfloat16(f);
  return __builtin_bit_cast(unsigned short, h);
}

// ---------------- fp32 -> bf16 weight convert ----------------
__global__ void cvt_kernel(const float* __restrict__ in, __hip_bfloat16* __restrict__ out, int n) {
  int i = blockIdx.x * 256 + threadIdx.x;
  if (i < n) out[i] = __float2bfloat16(in[i]);
}

// ---------------- LayerNorm (one wave per token row, C=256) ----------------
template<bool WIN>
__global__ __launch_bounds__(256) void ln_kernel(
    const float* __restrict__ xin, const float* __restrict__ g,
    const float* __restrict__ b, __hip_bfloat16* __restrict__ outb)
{
  int r = blockIdx.x * 4 + (threadIdx.x >> 6);
  int l = threadIdx.x & 63;
  int tok = WIN ? win_row_to_token(r) : r;
  float4 xv = *(const float4*)&xin[(size_t)tok * 256 + l * 4];
  float s = xv.x + xv.y + xv.z + xv.w;
  float q = xv.x * xv.x + xv.y * xv.y + xv.z * xv.z + xv.w * xv.w;
  #pragma unroll
  for (int off = 32; off; off >>= 1) { s += __shfl_xor(s, off); q += __shfl_xor(q, off); }
  float mu = s * (1.0f / 256.0f);
  float var = q * (1.0f / 256.0f) - mu * mu;
  float rs = rsqrtf(var + 1e-5f);
  float4 gv = *(const float4*)&g[l * 4];
  float4 bv = *(const float4*)&b[l * 4];
  ushort4 st;
  st.x = f2bf((xv.x - mu) * rs * gv.x + bv.x);
  st.y = f2bf((xv.y - mu) * rs * gv.y + bv.y);
  st.z = f2bf((xv.z - mu) * rs * gv.z + bv.z);
  st.w = f2bf((xv.w - mu) * rs * gv.w + bv.w);
  *(ushort4*)&outb[(size_t)r * 256 + l * 4] = st;
}

enum { EPI_QKV = 0, EPI_PROJ = 1, EPI_MLP1 = 2, EPI_MLP2 = 3 };

// ---------------- tiled MFMA GEMM: out(M,N) = A(M,K) * Bw(N,K)^T ----------------
// 128x128 tile, 4 waves (2x2), each wave 64x64 = 4x4 frags of 16x16x32.
// XCD-chunked swizzle, nt-fastest: bswz = (bid&7)*(nwg/8) + (bid>>3).
// -> each XCD owns a contiguous mt-range; the ntiles blocks sharing one A-panel
//    are adjacent in time on the same XCD (A: 1 HBM fetch + L2 hits; B L2-resident).
template<int EPI>
__global__ __launch_bounds__(256) void gemm_kernel(
    const __hip_bfloat16* __restrict__ A,
    const __hip_bfloat16* __restrict__ Bw,
    int N, int K,
    const float* __restrict__ bias,
    const float* __restrict__ xres,   // PROJ: original x (token order)
    float* __restrict__ outf,         // PROJ/MLP2: d_out
    __hip_bfloat16* __restrict__ outb)// QKV/MLP1
{
  __shared__ __align__(16) __hip_bfloat16 lsA[BM * BK];
  __shared__ __align__(16) __hip_bfloat16 lsB[BN * BK];
  const int ntiles = N / BN;
  const int nwg = gridDim.x;              // all grids here are %8==0
  int bswz = (blockIdx.x & 7) * (nwg >> 3) + (blockIdx.x >> 3);
  int mt = bswz / ntiles;
  int nt = bswz - mt * ntiles;
  const int w = threadIdx.x >> 6, l = threadIdx.x & 63;
  const int wr = (w >> 1) * 64, wc = (w & 1) * 64;
  f32x4 acc[4][4] = {};
  const __hip_bfloat16* Abase = A  + (size_t)mt * BM * K;
  const __hip_bfloat16* Bbase = Bw + (size_t)nt * BN * K;
  const int srow = l >> 3;
  const int skb  = (l & 7) * 8;

  for (int kt = 0; kt < K; kt += BK) {
    #pragma unroll
    for (int i = 0; i < 4; ++i) {
      int chunk = w * 4 + i;
      int row = chunk * 8 + srow;
      __builtin_amdgcn_global_load_lds(
          (const __attribute__((address_space(1))) void*)(Abase + (size_t)row * K + kt + skb),
          (__attribute__((address_space(3))) void*)(&lsA[chunk * 512]), 16, 0, 0);
      __builtin_amdgcn_global_load_lds(
          (const __attribute__((address_space(1))) void*)(Bbase + (size_t)row * K + kt + skb),
          (__attribute__((address_space(3))) void*)(&lsB[chunk * 512]), 16, 0, 0);
    }
    __syncthreads();
    #pragma unroll
    for (int kk = 0; kk < 2; ++kk) {
      bf16x8 af[4], bfr[4];
      #pragma unroll
      for (int mi = 0; mi < 4; ++mi)
        af[mi] = *(const bf16x8*)&lsA[(wr + mi * 16 + (l & 15)) * 64 + kk * 32 + (l >> 4) * 8];
      #pragma unroll
      for (int ni = 0; ni < 4; ++ni)
        bfr[ni] = *(const bf16x8*)&lsB[(wc + ni * 16 + (l & 15)) * 64 + kk * 32 + (l >> 4) * 8];
      #pragma unroll
      for (int mi = 0; mi < 4; ++mi)
        #pragma unroll
        for (int ni = 0; ni < 4; ++ni)
          acc[mi][ni] = __builtin_amdgcn_mfma_f32_16x16x32_bf16(af[mi], bfr[ni], acc[mi][ni], 0, 0, 0);
    }
    __syncthreads();
  }

  const int lcol = l & 15, lrow4 = (l >> 4) * 4;
  #pragma unroll
  for (int mi = 0; mi < 4; ++mi) {
    #pragma unroll
    for (int j = 0; j < 4; ++j) {
      int grow = mt * BM + wr + mi * 16 + lrow4 + j;
      int orow = grow;
      if (EPI == EPI_PROJ) orow = win_row_to_token(grow);
      #pragma unroll
      for (int ni = 0; ni < 4; ++ni) {
        int gcol = nt * BN + wc + ni * 16 + lcol;
        float v = acc[mi][ni][j] + bias[gcol];
        if (EPI == EPI_QKV) {
          outb[(size_t)grow * 768 + gcol] = __float2bfloat16(v);
        } else if (EPI == EPI_PROJ) {
          size_t o = (size_t)orow * 256 + gcol;
          outf[o] = xres[o] + v;                       // residual 1
        } else if (EPI == EPI_MLP1) {
          float ge = 0.5f * v * (1.0f + erff(v * 0.70710678118654752f));
          outb[(size_t)grow * 1024 + gcol] = __float2bfloat16(ge);
        } else { // MLP2
          size_t o = (size_t)grow * 256 + gcol;
          outf[o] += v;                                // residual 2 (in-place)
        }
      }
    }
  }
}

// ---------------- Sadd precompute: bias+mask in MFMA frag layout ----------------
__global__ __launch_bounds__(256) void bias_prep_kernel(
    const float* __restrict__ bt, float* __restrict__ Sadd)
{
  int blk = blockIdx.x;            // class*8 + h
  int cls = blk >> 3, h = blk & 7;
  int re = cls >> 1, ce = cls & 1;
  int lane = threadIdx.x & 63, fs = threadIdx.x >> 6;
  int g = lane >> 4, lm = lane & 15;
  #pragma unroll
  for (int i = 0; i < 4; ++i) {
    int f = fs * 4 + i;
    int mi = f >> 2, ni = f & 3;
    int key = ni * 16 + lm;
    f32x4 v;
    #pragma unroll
    for (int j = 0; j < 4; ++j) {
      int q = mi * 16 + g * 4 + j;
      float val;
      if (key >= 49) {
        val = -1e30f;
      } else {
        int qq = q > 48 ? 48 : q;
        int qh = qq / 7, qw = qq - qh * 7;
        int kh = key / 7, kw = key - kh * 7;
        int rpi = (qh - kh + 6) * 13 + (qw - kw + 6);
        val = bt[rpi * 8 + h];
        int rq = (re ? (qh < 4 ? 1 : 2) : 0) * 3 + (ce ? (qw < 4 ? 1 : 2) : 0);
        int rk = (re ? (kh < 4 ? 1 : 2) : 0) * 3 + (ce ? (kw < 4 ? 1 : 2) : 0);
        if (rq != rk) val -= 100.0f;
      }
      v[j] = val;
    }
    ((f32x4*)Sadd)[(blk * 16 + f) * 64 + lane] = v;
  }
}

// ---------------- MFMA attention: block = (window, 4 heads), wave = head ----------
__global__ __launch_bounds__(256) void attn_mfma_kernel(
    const __hip_bfloat16* __restrict__ qkv,
    const float* __restrict__ Sadd,
    __hip_bfloat16* __restrict__ attn_out)
{
  __shared__ __align__(16) __hip_bfloat16 Pl[4][64 * 72];
  int blk = blockIdx.x;
  int win = blk >> 1, half = blk & 1;
  int w = threadIdx.x >> 6, l = threadIdx.x & 63;
  int head = half * 4 + w;
  int g = l >> 4, lm = l & 15;
  int wi = win & 63;
  int cls = (((wi >> 3) == 7) ? 2 : 0) | (((wi & 7) == 7) ? 1 : 0);
  const __hip_bfloat16* base = qkv + (size_t)win * 49 * 768 + head * 32;

  bf16x8 aQ[4], bK[4];
  #pragma unroll
  for (int mi = 0; mi < 4; ++mi) {
    int q = mi * 16 + lm; if (q > 48) q = 48;
    aQ[mi] = *(const bf16x8*)(base + q * 768 + g * 8);
  }
  #pragma unroll
  for (int ni = 0; ni < 4; ++ni) {
    int k = ni * 16 + lm; if (k > 48) k = 48;
    bK[ni] = *(const bf16x8*)(base + 256 + k * 768 + g * 8);
  }
  f32x4 acc[4][4] = {};
  #pragma unroll
  for (int mi = 0; mi < 4; ++mi)
    #pragma unroll
    for (int ni = 0; ni < 4; ++ni)
      acc[mi][ni] = __builtin_amdgcn_mfma_f32_16x16x32_bf16(aQ[mi], bK[ni], acc[mi][ni], 0, 0, 0);

  const float scale = 0.17677669529663687f;
  const f32x4* Sb = (const f32x4*)Sadd + (size_t)(cls * 8 + head) * 16 * 64 + l;

  f32x4 rsum[4];
  __hip_bfloat16* P = Pl[w];
  #pragma unroll
  for (int mi = 0; mi < 4; ++mi) {
    #pragma unroll
    for (int ni = 0; ni < 4; ++ni) {
      f32x4 sv = Sb[(mi * 4 + ni) * 64];
      #pragma unroll
      for (int j = 0; j < 4; ++j) acc[mi][ni][j] = acc[mi][ni][j] * scale + sv[j];
    }
    f32x4 mx = acc[mi][0];
    #pragma unroll
    for (int ni = 1; ni < 4; ++ni)
      #pragma unroll
      for (int j = 0; j < 4; ++j) mx[j] = fmaxf(mx[j], acc[mi][ni][j]);
    #pragma unroll
    for (int msk = 1; msk < 16; msk <<= 1)
      #pragma unroll
      for (int j = 0; j < 4; ++j) mx[j] = fmaxf(mx[j], __shfl_xor(mx[j], msk));
    f32x4 sm = {};
    #pragma unroll
    for (int ni = 0; ni < 4; ++ni)
      #pragma unroll
      for (int j = 0; j < 4; ++j) {
        float e = __expf(acc[mi][ni][j] - mx[j]);
        acc[mi][ni][j] = e;
        sm[j] += e;
      }
    #pragma unroll
    for (int msk = 1; msk < 16; msk <<= 1)
      #pragma unroll
      for (int j = 0; j < 4; ++j) sm[j] += __shfl_xor(sm[j], msk);
    rsum[mi] = sm;
    #pragma unroll
    for (int ni = 0; ni < 4; ++ni)
      #pragma unroll
      for (int j = 0; j < 4; ++j) {
        int q = mi * 16 + g * 4 + j;
        int key = ni * 16 + lm;
        P[q * 72 + key] = __float2bfloat16(acc[mi][ni][j]);
      }
  }

  bf16x8 bV[2][2];
  #pragma unroll
  for (int s = 0; s < 2; ++s)
    #pragma unroll
    for (int n2 = 0; n2 < 2; ++n2) {
      bf16x8 vv;
      #pragma unroll
      for (int e = 0; e < 8; ++e) {
        int key = s * 32 + g * 8 + e; if (key > 48) key = 48;
        vv[e] = __builtin_bit_cast(short, base[512 + key * 768 + n2 * 16 + lm]);
      }
      bV[s][n2] = vv;
    }

  f32x4 o[4][2] = {};
  #pragma unroll
  for (int s = 0; s < 2; ++s)
    #pragma unroll
    for (int mi2 = 0; mi2 < 4; ++mi2) {
      bf16x8 aP = *(const bf16x8*)&P[(mi2 * 16 + lm) * 72 + s * 32 + g * 8];
      #pragma unroll
      for (int n2 = 0; n2 < 2; ++n2)
        o[mi2][n2] = __builtin_amdgcn_mfma_f32_16x16x32_bf16(aP, bV[s][n2], o[mi2][n2], 0, 0, 0);
    }

  #pragma unroll
  for (int mi2 = 0; mi2 < 4; ++mi2) {
    f32x4 li;
    #pragma unroll
    for (int j = 0; j < 4; ++j) li[j] = 1.0f / rsum[mi2][j];
    #pragma unroll
    for (int n2 = 0; n2 < 2; ++n2)
      #pragma unroll
      for (int j = 0; j < 4; ++j) {
        int q = mi2 * 16 + g * 4 + j;
        if (q < 49)
          attn_out[((size_t)win * 49 + q) * 256 + head * 32 + n2 * 16 + lm] =
              __float2bfloat16(o[mi2][n2][j] * li[j]);
      }
  }
}

// ---------------- host launch ----------------
extern "C" void kernel_launch(void* const* d_in, const int* in_sizes, int n_in,
                              void* d_out, int out_size, void* d_ws, size_t ws_size,
                              hipStream_t stream) {
  const float* x          = (const float*)d_in[0];
  const float* g1         = (const float*)d_in[1];
  const float* b1         = (const float*)d_in[2];
  const float* qkv_w      = (const float*)d_in[3];
  const float* qkv_b      = (const float*)d_in[4];
  const float* bias_table = (const float*)d_in[5];
  const float* proj_w     = (const float*)d_in[6];
  const float* proj_b     = (const float*)d_in[7];
  const float* g2         = (const float*)d_in[8];
  const float* b2         = (const float*)d_in[9];
  const float* w1         = (const float*)d_in[10];
  const float* bm1        = (const float*)d_in[11];
  const float* w2         = (const float*)d_in[12];
  const float* bm2        = (const float*)d_in[13];
  float* out = (float*)d_out;

  char* ws = (char*)d_ws;
  __hip_bfloat16* A_ln   = (__hip_bfloat16*)(ws);
  __hip_bfloat16* qkvb   = (__hip_bfloat16*)(ws + 51380224);
  __hip_bfloat16* attn_o = (__hip_bfloat16*)(ws + 205520896);
  __hip_bfloat16* hidden = qkvb;
  __hip_bfloat16* qkv_wb  = (__hip_bfloat16*)(ws + 256901120);
  __hip_bfloat16* proj_wb = qkv_wb + 196608;
  __hip_bfloat16* w1b     = proj_wb + 65536;
  __hip_bfloat16* w2b     = w1b + 262144;
  float* Sadd = (float*)(ws + 258473984);

  cvt_kernel<<<(196608 + 255) / 256, 256, 0, stream>>>(qkv_w, qkv_wb, 196608);
  cvt_kernel<<<(65536  + 255) / 256, 256, 0, stream>>>(proj_w, proj_wb, 65536);
  cvt_kernel<<<(262144 + 255) / 256, 256, 0, stream>>>(w1, w1b, 262144);
  cvt_kernel<<<(262144 + 255) / 256, 256, 0, stream>>>(w2, w2b, 262144);
  bias_prep_kernel<<<32, 256, 0, stream>>>(bias_table, Sadd);

  ln_kernel<true><<<MROWS / 4, 256, 0, stream>>>(x, g1, b1, A_ln);

  gemm_kernel<EPI_QKV><<<(MROWS / BM) * (768 / BN), 256, 0, stream>>>(
      A_ln, qkv_wb, 768, 256, qkv_b, nullptr, nullptr, qkvb);

  attn_mfma_kernel<<<4096, 256, 0, stream>>>(qkvb, Sadd, attn_o);

  gemm_kernel<EPI_PROJ><<<(MROWS / BM) * (256 / BN), 256, 0, stream>>>(
      attn_o, proj_wb, 256, 256, proj_b, x, out, nullptr);

  ln_kernel<false><<<MROWS / 4, 256, 0, stream>>>(out, g2, b2, A_ln);

  gemm_kernel<EPI_MLP1><<<(MROWS / BM) * (1024 / BN), 256, 0, stream>>>(
      A_ln, w1b, 1024, 256, bm1, nullptr, nullptr, hidden);

  gemm_kernel<EPI_MLP2><<<(MROWS / BM) * (256 / BN), 256, 0, stream>>>(
      hidden, w2b, 256, 1024, bm2, nullptr, out, nullptr);
}

// Round 7
// 529.979 us; speedup vs baseline: 1.3450x; 1.0796x over previous
//
#include <hip/hip_runtime.h>
#include <hip/hip_bf16.h>

#define DEVI __device__ __forceinline__
#define AS1 __attribute__((address_space(1)))
#define AS3 __attribute__((address_space(3)))

typedef short bf16x8 __attribute__((ext_vector_type(8)));
typedef float f32x4  __attribute__((ext_vector_type(4)));

// Problem constants (B=32, H=W=56, C=256, wh=ww=7, shift=3, heads=8, hd=32)
constexpr int MROWS = 100352;            // 32 * 64 * 49 window-order rows

// window-order row -> flat token index (b*3136 + h*56 + w).
DEVI int win_row_to_token(int r) {
  int b   = r / 3136;
  int rem = r - b * 3136;
  int wi  = rem / 49;
  int t   = rem - wi * 49;
  int nwh = wi >> 3, nww = wi & 7;
  int th = t / 7, tw = t - th * 7;
  int h = nwh * 7 + th + 3; if (h >= 56) h -= 56;
  int w = nww * 7 + tw + 3; if (w >= 56) w -= 56;
  return b * 3136 + h * 56 + w;
}

DEVI unsigned short f2bf(float f) {
  __hip_bfloat16 h = __float2bfloat16(f);
  return __builtin_bit_cast(unsigned short, h);
}

// ---------------- fp32 -> bf16 weight convert ----------------
__global__ void cvt_kernel(const float* __restrict__ in, __hip_bfloat16* __restrict__ out, int n) {
  int i = blockIdx.x * 256 + threadIdx.x;
  if (i < n) out[i] = __float2bfloat16(in[i]);
}

// ---------------- LayerNorm (one wave per token row, C=256) ----------------
template<bool WIN>
__global__ __launch_bounds__(256) void ln_kernel(
    const float* __restrict__ xin, const float* __restrict__ g,
    const float* __restrict__ b, __hip_bfloat16* __restrict__ outb)
{
  int r = blockIdx.x * 4 + (threadIdx.x >> 6);
  int l = threadIdx.x & 63;
  int tok = WIN ? win_row_to_token(r) : r;
  float4 xv = *(const float4*)&xin[(size_t)tok * 256 + l * 4];
  float s = xv.x + xv.y + xv.z + xv.w;
  float q = xv.x * xv.x + xv.y * xv.y + xv.z * xv.z + xv.w * xv.w;
  #pragma unroll
  for (int off = 32; off; off >>= 1) { s += __shfl_xor(s, off); q += __shfl_xor(q, off); }
  float mu = s * (1.0f / 256.0f);
  float var = q * (1.0f / 256.0f) - mu * mu;
  float rs = rsqrtf(var + 1e-5f);
  float4 gv = *(const float4*)&g[l * 4];
  float4 bv = *(const float4*)&b[l * 4];
  ushort4 st;
  st.x = f2bf((xv.x - mu) * rs * gv.x + bv.x);
  st.y = f2bf((xv.y - mu) * rs * gv.y + bv.y);
  st.z = f2bf((xv.z - mu) * rs * gv.z + bv.z);
  st.w = f2bf((xv.w - mu) * rs * gv.w + bv.w);
  *(ushort4*)&outb[(size_t)r * 256 + l * 4] = st;
}

enum { EPI_QKV = 0, EPI_PROJ = 1, EPI_MLP1 = 2, EPI_MLP2 = 3 };

// ------------- persistent strip GEMM: B-panel in LDS, A streamed -------------
// 256 blocks (1/CU), 512 thr = 8 waves (4 M-rows x 2 N-cols), wave tile 64x64,
// block tile 256(M) x 128(N). LDS: B panel [128n][256k] = 64KB (XOR-swizzled),
// A double-buffer 2 x [256m][64k] = 64KB. Block sweeps tiles t in [t0,t1) of its
// XCD chunk, nt-major (B stays resident; A L2-local). One continuous pipeline:
// per chunk: [restage B if (nt,kb) changed] issue A(next) -> vmcnt(4)
//            -> s_barrier -> compute -> s_barrier   (R4-validated discipline)
// KTOT=1024 (MLP2): B restaged per kb quarter (L2-hot), acc persists across kb.
template<int EPI, int KTOT>
__global__ __launch_bounds__(512, 1) void strip2(
    const __hip_bfloat16* __restrict__ A,
    const __hip_bfloat16* __restrict__ Bw,
    int ntiles,                        // N/128
    const float* __restrict__ bias,
    const float* __restrict__ xres,    // PROJ: original x (token order)
    float* __restrict__ outf,          // PROJ/MLP2: d_out
    __hip_bfloat16* __restrict__ outb) // QKV/MLP1
{
  constexpr int NC = KTOT / 64;        // chunks per tile (4 or 16)
  __shared__ __align__(16) __hip_bfloat16 Bl[128 * 256];     // 64KB
  __shared__ __align__(16) __hip_bfloat16 Al[2][256 * 64];   // 2 x 32KB

  const int tid = threadIdx.x;
  const int w = tid >> 6, l = tid & 63;
  const int wr = w >> 1, wc = w & 1;   // 4 M-waves x 2 N-waves
  const int g = l >> 4, lm = l & 15;

  const int xcd = blockIdx.x & 7;
  const int cu  = blockIdx.x >> 3;     // 0..31
  const int T   = 49 * ntiles;         // tiles in XCD chunk (49 mt each)
  const int t0  = (cu * T) >> 5;
  const int t1  = ((cu + 1) * T) >> 5;
  const int nchunks = (t1 - t0) * NC;

  // stage A chunk (mt, c) -> Al[buf]. 2048 16B-units; 4 global_load_lds/thread.
  // LDS unit U=row*8+i holds global unit row*8+(i^(row&7)) (src pre-swizzle).
  auto issueA = [&](int mt, int c, int buf) {
    const __hip_bfloat16* Ab = A + (size_t)mt * 256 * KTOT + c * 64;
    #pragma unroll
    for (int j = 0; j < 4; ++j) {
      int U = j * 512 + w * 64 + l;
      int row = U >> 3;
      int su = (U & 7) ^ (row & 7);
      __builtin_amdgcn_global_load_lds(
          (const AS1 void*)((const char*)(Ab + (size_t)row * KTOT) + su * 16),
          (AS3 void*)(&Al[buf][(j * 512 + w * 64) * 8]), 16, 0, 0);
    }
  };
  // stage B slice (nt, kb) -> Bl. 4096 16B-units; 8 global_load_lds/thread.
  auto stageB = [&](int nt, int kb) {
    const __hip_bfloat16* Bb = Bw + (size_t)nt * 128 * KTOT + kb * 256;
    #pragma unroll
    for (int j = 0; j < 8; ++j) {
      int U = j * 512 + w * 64 + l;
      int row = U >> 5;
      int su = (U & 31) ^ (row & 7);
      __builtin_amdgcn_global_load_lds(
          (const AS1 void*)((const char*)(Bb + (size_t)row * KTOT) + su * 16),
          (AS3 void*)(&Bl[(j * 512 + w * 64) * 8]), 16, 0, 0);
    }
  };

  f32x4 acc[4][4];
  int pB_nt = -1, pB_kb = -1;
  int p = 0;

  {
    int nt0 = t0 / 49;
    stageB(nt0, 0); pB_nt = nt0; pB_kb = 0;
    int mt0 = xcd * 49 + (t0 - nt0 * 49);
    issueA(mt0, 0, 0);
  }

  for (int q = 0; q < nchunks; ++q) {
    int t  = t0 + q / NC;
    int c  = q - (q / NC) * NC;
    int nt = t / 49;
    int mt = xcd * 49 + (t - nt * 49);
    int kb = (KTOT == 1024) ? (c >> 2) : 0;

    if (nt != pB_nt || kb != pB_kb) {  // after previous chunk's trailing barrier
      stageB(nt, kb); pB_nt = nt; pB_kb = kb;
    }
    if (c == 0) {
      #pragma unroll
      for (int mi = 0; mi < 4; ++mi)
        #pragma unroll
        for (int ni = 0; ni < 4; ++ni)
          acc[mi][ni] = f32x4{0.f, 0.f, 0.f, 0.f};
    }

    if (q != nchunks - 1) {
      int qn = q + 1;
      int tn = t0 + qn / NC;
      int cn = qn - (qn / NC) * NC;
      int ntn = tn / 49;
      issueA(xcd * 49 + (tn - ntn * 49), cn, p ^ 1);
      asm volatile("s_waitcnt vmcnt(4)" ::: "memory");   // own A(q)+B done; A(q+1) in flight
    } else {
      asm volatile("s_waitcnt vmcnt(0)" ::: "memory");
    }
    __builtin_amdgcn_s_barrier();
    asm volatile("" ::: "memory");

    #pragma unroll
    for (int kk = 0; kk < 2; ++kk) {
      bf16x8 af[4], bfr[4];
      #pragma unroll
      for (int mi = 0; mi < 4; ++mi) {
        int r = wr * 64 + mi * 16 + lm;
        int u = (kk * 4 + g) ^ (r & 7);
        af[mi] = *(const bf16x8*)&Al[p][r * 64 + u * 8];
      }
      #pragma unroll
      for (int ni = 0; ni < 4; ++ni) {
        int rn = wc * 64 + ni * 16 + lm;
        int u = ((c & 3) * 8 + kk * 4 + g) ^ (rn & 7);
        bfr[ni] = *(const bf16x8*)&Bl[rn * 256 + u * 8];
      }
      #pragma unroll
      for (int mi = 0; mi < 4; ++mi)
        #pragma unroll
        for (int ni = 0; ni < 4; ++ni)
          acc[mi][ni] = __builtin_amdgcn_mfma_f32_16x16x32_bf16(
              af[mi], bfr[ni], acc[mi][ni], 0, 0, 0);
    }
    asm volatile("" ::: "memory");
    __builtin_amdgcn_s_barrier();
    p ^= 1;

    if (c == NC - 1) {
      // ---- tile epilogue (regs+global only; safe after trailing barrier) ----
      #pragma unroll
      for (int mi = 0; mi < 4; ++mi)
        #pragma unroll
        for (int j = 0; j < 4; ++j) {
          int grow = mt * 256 + wr * 64 + mi * 16 + g * 4 + j;
          int orow = grow;
          if (EPI == EPI_PROJ) orow = win_row_to_token(grow);
          #pragma unroll
          for (int ni = 0; ni < 4; ++ni) {
            int gcol = nt * 128 + wc * 64 + ni * 16 + lm;
            float v = acc[mi][ni][j] + bias[gcol];
            if (EPI == EPI_QKV) {
              outb[(size_t)grow * 768 + gcol] = __float2bfloat16(v);
            } else if (EPI == EPI_PROJ) {
              size_t o = (size_t)orow * 256 + gcol;
              outf[o] = xres[o] + v;                       // residual 1
            } else if (EPI == EPI_MLP1) {
              float ge = 0.5f * v * (1.0f + erff(v * 0.70710678118654752f));
              outb[(size_t)grow * 1024 + gcol] = __float2bfloat16(ge);
            } else { // MLP2
              size_t o = (size_t)grow * 256 + gcol;
              outf[o] += v;                                // residual 2 (in-place)
            }
          }
        }
    }
  }
}

// ---------------- Sadd precompute: bias+mask in MFMA frag layout ----------------
__global__ __launch_bounds__(256) void bias_prep_kernel(
    const float* __restrict__ bt, float* __restrict__ Sadd)
{
  int blk = blockIdx.x;            // class*8 + h
  int cls = blk >> 3, h = blk & 7;
  int re = cls >> 1, ce = cls & 1;
  int lane = threadIdx.x & 63, fs = threadIdx.x >> 6;
  int g = lane >> 4, lm = lane & 15;
  #pragma unroll
  for (int i = 0; i < 4; ++i) {
    int f = fs * 4 + i;
    int mi = f >> 2, ni = f & 3;
    int key = ni * 16 + lm;
    f32x4 v;
    #pragma unroll
    for (int j = 0; j < 4; ++j) {
      int q = mi * 16 + g * 4 + j;
      float val;
      if (key >= 49) {
        val = -1e30f;
      } else {
        int qq = q > 48 ? 48 : q;
        int qh = qq / 7, qw = qq - qh * 7;
        int kh = key / 7, kw = key - kh * 7;
        int rpi = (qh - kh + 6) * 13 + (qw - kw + 6);
        val = bt[rpi * 8 + h];
        int rq = (re ? (qh < 4 ? 1 : 2) : 0) * 3 + (ce ? (qw < 4 ? 1 : 2) : 0);
        int rk = (re ? (kh < 4 ? 1 : 2) : 0) * 3 + (ce ? (kw < 4 ? 1 : 2) : 0);
        if (rq != rk) val -= 100.0f;
      }
      v[j] = val;
    }
    ((f32x4*)Sadd)[(blk * 16 + f) * 64 + lane] = v;
  }
}

// ---------------- MFMA attention: block = (window, 4 heads), wave = head ----------
__global__ __launch_bounds__(256) void attn_mfma_kernel(
    const __hip_bfloat16* __restrict__ qkv,
    const float* __restrict__ Sadd,
    __hip_bfloat16* __restrict__ attn_out)
{
  __shared__ __align__(16) __hip_bfloat16 Pl[4][64 * 72];
  int blk = blockIdx.x;
  int win = blk >> 1, half = blk & 1;
  int w = threadIdx.x >> 6, l = threadIdx.x & 63;
  int head = half * 4 + w;
  int g = l >> 4, lm = l & 15;
  int wi = win & 63;
  int cls = (((wi >> 3) == 7) ? 2 : 0) | (((wi & 7) == 7) ? 1 : 0);
  const __hip_bfloat16* base = qkv + (size_t)win * 49 * 768 + head * 32;

  bf16x8 aQ[4], bK[4];
  #pragma unroll
  for (int mi = 0; mi < 4; ++mi) {
    int q = mi * 16 + lm; if (q > 48) q = 48;
    aQ[mi] = *(const bf16x8*)(base + q * 768 + g * 8);
  }
  #pragma unroll
  for (int ni = 0; ni < 4; ++ni) {
    int k = ni * 16 + lm; if (k > 48) k = 48;
    bK[ni] = *(const bf16x8*)(base + 256 + k * 768 + g * 8);
  }
  f32x4 acc[4][4] = {};
  #pragma unroll
  for (int mi = 0; mi < 4; ++mi)
    #pragma unroll
    for (int ni = 0; ni < 4; ++ni)
      acc[mi][ni] = __builtin_amdgcn_mfma_f32_16x16x32_bf16(aQ[mi], bK[ni], acc[mi][ni], 0, 0, 0);

  const float scale = 0.17677669529663687f;
  const f32x4* Sb = (const f32x4*)Sadd + (size_t)(cls * 8 + head) * 16 * 64 + l;

  f32x4 rsum[4];
  __hip_bfloat16* P = Pl[w];
  #pragma unroll
  for (int mi = 0; mi < 4; ++mi) {
    #pragma unroll
    for (int ni = 0; ni < 4; ++ni) {
      f32x4 sv = Sb[(mi * 4 + ni) * 64];
      #pragma unroll
      for (int j = 0; j < 4; ++j) acc[mi][ni][j] = acc[mi][ni][j] * scale + sv[j];
    }
    f32x4 mx = acc[mi][0];
    #pragma unroll
    for (int ni = 1; ni < 4; ++ni)
      #pragma unroll
      for (int j = 0; j < 4; ++j) mx[j] = fmaxf(mx[j], acc[mi][ni][j]);
    #pragma unroll
    for (int msk = 1; msk < 16; msk <<= 1)
      #pragma unroll
      for (int j = 0; j < 4; ++j) mx[j] = fmaxf(mx[j], __shfl_xor(mx[j], msk));
    f32x4 sm = {};
    #pragma unroll
    for (int ni = 0; ni < 4; ++ni)
      #pragma unroll
      for (int j = 0; j < 4; ++j) {
        float e = __expf(acc[mi][ni][j] - mx[j]);
        acc[mi][ni][j] = e;
        sm[j] += e;
      }
    #pragma unroll
    for (int msk = 1; msk < 16; msk <<= 1)
      #pragma unroll
      for (int j = 0; j < 4; ++j) sm[j] += __shfl_xor(sm[j], msk);
    rsum[mi] = sm;
    #pragma unroll
    for (int ni = 0; ni < 4; ++ni)
      #pragma unroll
      for (int j = 0; j < 4; ++j) {
        int q = mi * 16 + g * 4 + j;
        int key = ni * 16 + lm;
        P[q * 72 + key] = __float2bfloat16(acc[mi][ni][j]);
      }
  }

  bf16x8 bV[2][2];
  #pragma unroll
  for (int s = 0; s < 2; ++s)
    #pragma unroll
    for (int n2 = 0; n2 < 2; ++n2) {
      bf16x8 vv;
      #pragma unroll
      for (int e = 0; e < 8; ++e) {
        int key = s * 32 + g * 8 + e; if (key > 48) key = 48;
        vv[e] = __builtin_bit_cast(short, base[512 + key * 768 + n2 * 16 + lm]);
      }
      bV[s][n2] = vv;
    }

  f32x4 o[4][2] = {};
  #pragma unroll
  for (int s = 0; s < 2; ++s)
    #pragma unroll
    for (int mi2 = 0; mi2 < 4; ++mi2) {
      bf16x8 aP = *(const bf16x8*)&P[(mi2 * 16 + lm) * 72 + s * 32 + g * 8];
      #pragma unroll
      for (int n2 = 0; n2 < 2; ++n2)
        o[mi2][n2] = __builtin_amdgcn_mfma_f32_16x16x32_bf16(aP, bV[s][n2], o[mi2][n2], 0, 0, 0);
    }

  #pragma unroll
  for (int mi2 = 0; mi2 < 4; ++mi2) {
    f32x4 li;
    #pragma unroll
    for (int j = 0; j < 4; ++j) li[j] = 1.0f / rsum[mi2][j];
    #pragma unroll
    for (int n2 = 0; n2 < 2; ++n2)
      #pragma unroll
      for (int j = 0; j < 4; ++j) {
        int q = mi2 * 16 + g * 4 + j;
        if (q < 49)
          attn_out[((size_t)win * 49 + q) * 256 + head * 32 + n2 * 16 + lm] =
              __float2bfloat16(o[mi2][n2][j] * li[j]);
      }
  }
}

// ---------------- host launch ----------------
extern "C" void kernel_launch(void* const* d_in, const int* in_sizes, int n_in,
                              void* d_out, int out_size, void* d_ws, size_t ws_size,
                              hipStream_t stream) {
  const float* x          = (const float*)d_in[0];
  const float* g1         = (const float*)d_in[1];
  const float* b1         = (const float*)d_in[2];
  const float* qkv_w      = (const float*)d_in[3];
  const float* qkv_b      = (const float*)d_in[4];
  const float* bias_table = (const float*)d_in[5];
  const float* proj_w     = (const float*)d_in[6];
  const float* proj_b     = (const float*)d_in[7];
  const float* g2         = (const float*)d_in[8];
  const float* b2         = (const float*)d_in[9];
  const float* w1         = (const float*)d_in[10];
  const float* bm1        = (const float*)d_in[11];
  const float* w2         = (const float*)d_in[12];
  const float* bm2        = (const float*)d_in[13];
  float* out = (float*)d_out;

  char* ws = (char*)d_ws;
  __hip_bfloat16* A_ln   = (__hip_bfloat16*)(ws);
  __hip_bfloat16* qkvb   = (__hip_bfloat16*)(ws + 51380224);
  __hip_bfloat16* attn_o = (__hip_bfloat16*)(ws + 205520896);
  __hip_bfloat16* hidden = qkvb;
  __hip_bfloat16* qkv_wb  = (__hip_bfloat16*)(ws + 256901120);
  __hip_bfloat16* proj_wb = qkv_wb + 196608;
  __hip_bfloat16* w1b     = proj_wb + 65536;
  __hip_bfloat16* w2b     = w1b + 262144;
  float* Sadd = (float*)(ws + 258473984);

  cvt_kernel<<<(196608 + 255) / 256, 256, 0, stream>>>(qkv_w, qkv_wb, 196608);
  cvt_kernel<<<(65536  + 255) / 256, 256, 0, stream>>>(proj_w, proj_wb, 65536);
  cvt_kernel<<<(262144 + 255) / 256, 256, 0, stream>>>(w1, w1b, 262144);
  cvt_kernel<<<(262144 + 255) / 256, 256, 0, stream>>>(w2, w2b, 262144);
  bias_prep_kernel<<<32, 256, 0, stream>>>(bias_table, Sadd);

  ln_kernel<true><<<MROWS / 4, 256, 0, stream>>>(x, g1, b1, A_ln);

  strip2<EPI_QKV, 256><<<256, 512, 0, stream>>>(
      A_ln, qkv_wb, 6, qkv_b, nullptr, nullptr, qkvb);

  attn_mfma_kernel<<<4096, 256, 0, stream>>>(qkvb, Sadd, attn_o);

  strip2<EPI_PROJ, 256><<<256, 512, 0, stream>>>(
      attn_o, proj_wb, 2, proj_b, x, out, nullptr);

  ln_kernel<false><<<MROWS / 4, 256, 0, stream>>>(out, g2, b2, A_ln);

  strip2<EPI_MLP1, 256><<<256, 512, 0, stream>>>(
      A_ln, w1b, 8, bm1, nullptr, nullptr, hidden);

  strip2<EPI_MLP2, 1024><<<256, 512, 0, stream>>>(
      hidden, w2b, 2, bm2, nullptr, out, nullptr);
}

// Round 8
// 498.748 us; speedup vs baseline: 1.4292x; 1.0626x over previous
//
#include <hip/hip_runtime.h>
#include <hip/hip_bf16.h>

#define DEVI __device__ __forceinline__
#define AS1 __attribute__((address_space(1)))
#define AS3 __attribute__((address_space(3)))

typedef short bf16x8 __attribute__((ext_vector_type(8)));
typedef float f32x4  __attribute__((ext_vector_type(4)));

// Problem constants (B=32, H=W=56, C=256, wh=ww=7, shift=3, heads=8, hd=32)
constexpr int MROWS = 100352;            // 32 * 64 * 49 window-order rows

// window-order row -> flat token index (b*3136 + h*56 + w).
DEVI int win_row_to_token(int r) {
  int b   = r / 3136;
  int rem = r - b * 3136;
  int wi  = rem / 49;
  int t   = rem - wi * 49;
  int nwh = wi >> 3, nww = wi & 7;
  int th = t / 7, tw = t - th * 7;
  int h = nwh * 7 + th + 3; if (h >= 56) h -= 56;
  int w = nww * 7 + tw + 3; if (w >= 56) w -= 56;
  return b * 3136 + h * 56 + w;
}

DEVI unsigned short f2bf(float f) {
  __hip_bfloat16 h = __float2bfloat16(f);
  return __builtin_bit_cast(unsigned short, h);
}

// ---------------- fp32 -> bf16 weight convert ----------------
__global__ void cvt_kernel(const float* __restrict__ in, __hip_bfloat16* __restrict__ out, int n) {
  int i = blockIdx.x * 256 + threadIdx.x;
  if (i < n) out[i] = __float2bfloat16(in[i]);
}

// ---------------- LayerNorm (one wave per token row, C=256) ----------------
template<bool WIN>
__global__ __launch_bounds__(256) void ln_kernel(
    const float* __restrict__ xin, const float* __restrict__ g,
    const float* __restrict__ b, __hip_bfloat16* __restrict__ outb)
{
  int r = blockIdx.x * 4 + (threadIdx.x >> 6);
  int l = threadIdx.x & 63;
  int tok = WIN ? win_row_to_token(r) : r;
  float4 xv = *(const float4*)&xin[(size_t)tok * 256 + l * 4];
  float s = xv.x + xv.y + xv.z + xv.w;
  float q = xv.x * xv.x + xv.y * xv.y + xv.z * xv.z + xv.w * xv.w;
  #pragma unroll
  for (int off = 32; off; off >>= 1) { s += __shfl_xor(s, off); q += __shfl_xor(q, off); }
  float mu = s * (1.0f / 256.0f);
  float var = q * (1.0f / 256.0f) - mu * mu;
  float rs = rsqrtf(var + 1e-5f);
  float4 gv = *(const float4*)&g[l * 4];
  float4 bv = *(const float4*)&b[l * 4];
  ushort4 st;
  st.x = f2bf((xv.x - mu) * rs * gv.x + bv.x);
  st.y = f2bf((xv.y - mu) * rs * gv.y + bv.y);
  st.z = f2bf((xv.z - mu) * rs * gv.z + bv.z);
  st.w = f2bf((xv.w - mu) * rs * gv.w + bv.w);
  *(ushort4*)&outb[(size_t)r * 256 + l * 4] = st;
}

enum { EPI_QKV = 0, EPI_PROJ = 1, EPI_MLP1 = 2, EPI_MLP2 = 3 };

// ------------- persistent strip GEMM v3: hoisted addressing -------------
// Same geometry+sync as R7 strip2 (validated): 256 blocks, 8 waves (4Mx2N),
// wave tile 64x64, block tile 256x128; B panel [128n][256k] in LDS (64KB),
// A double-buffered 2x32KB; per chunk: [stageB?] issueA(next) -> vmcnt(4)
// -> s_barrier -> compute -> s_barrier.
// v3: all LDS/global addresses hoisted to per-lane constants + immediates;
// buffer index compile-time (chunks/tile even); no divisions in hot loop.
template<int EPI, int KTOT>
__global__ __launch_bounds__(512, 1) void strip3(
    const __hip_bfloat16* __restrict__ A,
    const __hip_bfloat16* __restrict__ Bw,
    int ntiles,                        // N/128
    const float* __restrict__ bias,
    const float* __restrict__ xres,    // PROJ: original x (token order)
    float* __restrict__ outf,          // PROJ/MLP2: d_out
    __hip_bfloat16* __restrict__ outb) // QKV/MLP1
{
  constexpr int NKB = KTOT / 256;            // B slices per tile (1 or 4)
  constexpr int NCH = NKB * 4;               // chunks per tile (even!)
  constexpr long TSTRIDE = 256L * KTOT * 2;  // A tile byte stride
  __shared__ __align__(16) __hip_bfloat16 Bl[128 * 256];     // 64KB
  __shared__ __align__(16) __hip_bfloat16 Al[2][256 * 64];   // 2 x 32KB

  const int tid = threadIdx.x;
  const int w = tid >> 6, l = tid & 63;
  const int wr = w >> 1, wc = w & 1;         // 4 M-waves x 2 N-waves
  const int g = l >> 4, lm = l & 15;

  const int xcd = blockIdx.x & 7;
  const int cu  = blockIdx.x >> 3;
  const int T   = 49 * ntiles;
  const int t0  = (cu * T) >> 5;
  const int t1  = ((cu + 1) * T) >> 5;

  char* AlB = (char*)&Al[0][0];
  char* BlB = (char*)&Bl[0];

  // ---- per-lane hoisted constants ----
  const int  dstW = w * 1024;                 // LDS stage dst (wave-uniform; HW adds lane*16)
  const long aoff = (long)(w * 8 + (l >> 3)) * (KTOT * 2) + (((l & 7) ^ (l >> 3)) << 4);
  const int  bA   = wr * 8192  + lm * 128 + ((g ^ (lm & 7)) << 4);   // ^kk*64, +mi*2048, +(chunk&1)*32768
  const int  bB   = wc * 32768 + lm * 512 + ((g ^ (lm & 7)) << 4);   // ^kk*64, +c*128, +ni*8192

  int nt = t0 / 49;
  int mtoff = t0 - nt * 49;
  const char* Ab = (const char*)A;
  const char* At = Ab + (long)(xcd * 49 + mtoff) * TSTRIDE;

  auto issueA = [&](const char* Atile, int coff, int buf) {
    #pragma unroll
    for (int j = 0; j < 4; ++j)
      __builtin_amdgcn_global_load_lds(
          (const AS1 void*)(Atile + aoff + j * (64L * KTOT * 2) + coff),
          (AS3 void*)(AlB + buf * 32768 + j * 8192 + dstW), 16, 0, 0);
  };
  auto stageB = [&](int nt_, int kb_) {
    const char* Bb = (const char*)(Bw + (size_t)nt_ * 128 * KTOT + kb_ * 256);
    #pragma unroll
    for (int j = 0; j < 8; ++j) {
      int U = j * 512 + w * 64 + l;
      int row = U >> 5;
      int su = (U & 31) ^ (row & 7);
      __builtin_amdgcn_global_load_lds(
          (const AS1 void*)(Bb + (long)row * (KTOT * 2) + su * 16),
          (AS3 void*)(BlB + j * 8192 + dstW), 16, 0, 0);
    }
  };

  // ---- prologue ----
  stageB(nt, 0);
  int sBnt = nt, sBkb = 0;
  issueA(At, 0, 0);

  f32x4 acc[4][4];
  for (int t = t0; t < t1; ++t) {
    const bool wrap = (mtoff == 48);
    const char* Atn = wrap ? (Ab + (long)(xcd * 49) * TSTRIDE) : (At + TSTRIDE);
    #pragma unroll
    for (int mi = 0; mi < 4; ++mi)
      #pragma unroll
      for (int ni = 0; ni < 4; ++ni)
        acc[mi][ni] = f32x4{0.f, 0.f, 0.f, 0.f};

    #pragma unroll
    for (int kb = 0; kb < NKB; ++kb) {
      if (sBnt != nt || sBkb != kb) { stageB(nt, kb); sBnt = nt; sBkb = kb; }
      #pragma unroll
      for (int c = 0; c < 4; ++c) {
        const int chunk = kb * 4 + c;
        if (chunk == NCH - 1) {
          if (t == t1 - 1) {
            asm volatile("s_waitcnt vmcnt(0)" ::: "memory");
          } else {
            issueA(Atn, 0, 0);                        // next tile chunk 0 -> buf 0
            asm volatile("s_waitcnt vmcnt(4)" ::: "memory");
          }
        } else {
          issueA(At, (chunk + 1) * 128, (chunk + 1) & 1);
          asm volatile("s_waitcnt vmcnt(4)" ::: "memory");
        }
        __builtin_amdgcn_s_barrier();
        asm volatile("" ::: "memory");

        #pragma unroll
        for (int kk = 0; kk < 2; ++kk) {
          bf16x8 af[4], bf[4];
          const int ax = bA ^ (kk * 64);
          const int bx = bB ^ (kk * 64);
          #pragma unroll
          for (int mi = 0; mi < 4; ++mi)
            af[mi] = *(const bf16x8*)(AlB + (chunk & 1) * 32768 + ax + mi * 2048);
          #pragma unroll
          for (int ni = 0; ni < 4; ++ni)
            bf[ni] = *(const bf16x8*)(BlB + bx + c * 128 + ni * 8192);
          #pragma unroll
          for (int mi = 0; mi < 4; ++mi)
            #pragma unroll
            for (int ni = 0; ni < 4; ++ni)
              acc[mi][ni] = __builtin_amdgcn_mfma_f32_16x16x32_bf16(
                  af[mi], bf[ni], acc[mi][ni], 0, 0, 0);
        }
        asm volatile("" ::: "memory");
        __builtin_amdgcn_s_barrier();
      }
    }

    // ---- tile epilogue ----
    {
      const int mt = xcd * 49 + mtoff;
      #pragma unroll
      for (int mi = 0; mi < 4; ++mi)
        #pragma unroll
        for (int j = 0; j < 4; ++j) {
          int grow = mt * 256 + wr * 64 + mi * 16 + g * 4 + j;
          int orow = grow;
          if (EPI == EPI_PROJ) orow = win_row_to_token(grow);
          #pragma unroll
          for (int ni = 0; ni < 4; ++ni) {
            int gcol = nt * 128 + wc * 64 + ni * 16 + lm;
            float v = acc[mi][ni][j] + bias[gcol];
            if (EPI == EPI_QKV) {
              outb[(size_t)grow * 768 + gcol] = __float2bfloat16(v);
            } else if (EPI == EPI_PROJ) {
              size_t o = (size_t)orow * 256 + gcol;
              outf[o] = xres[o] + v;                       // residual 1
            } else if (EPI == EPI_MLP1) {
              // tanh-form GELU: v * sigmoid(2*0.7978845608*(v + 0.044715 v^3))
              float u2 = v * (1.5957691216f + 0.1426930877f * v * v);
              float e  = __expf(u2);
              float ge = v * e / (e + 1.0f);
              outb[(size_t)grow * 1024 + gcol] = __float2bfloat16(ge);
            } else { // MLP2
              size_t o = (size_t)grow * 256 + gcol;
              outf[o] += v;                                // residual 2 (in-place)
            }
          }
        }
    }

    At = Atn;
    if (wrap) { mtoff = 0; ++nt; } else { ++mtoff; }
  }
}

// ---------------- Sadd precompute: bias+mask in MFMA frag layout ----------------
__global__ __launch_bounds__(256) void bias_prep_kernel(
    const float* __restrict__ bt, float* __restrict__ Sadd)
{
  int blk = blockIdx.x;            // class*8 + h
  int cls = blk >> 3, h = blk & 7;
  int re = cls >> 1, ce = cls & 1;
  int lane = threadIdx.x & 63, fs = threadIdx.x >> 6;
  int g = lane >> 4, lm = lane & 15;
  #pragma unroll
  for (int i = 0; i < 4; ++i) {
    int f = fs * 4 + i;
    int mi = f >> 2, ni = f & 3;
    int key = ni * 16 + lm;
    f32x4 v;
    #pragma unroll
    for (int j = 0; j < 4; ++j) {
      int q = mi * 16 + g * 4 + j;
      float val;
      if (key >= 49) {
        val = -1e30f;
      } else {
        int qq = q > 48 ? 48 : q;
        int qh = qq / 7, qw = qq - qh * 7;
        int kh = key / 7, kw = key - kh * 7;
        int rpi = (qh - kh + 6) * 13 + (qw - kw + 6);
        val = bt[rpi * 8 + h];
        int rq = (re ? (qh < 4 ? 1 : 2) : 0) * 3 + (ce ? (qw < 4 ? 1 : 2) : 0);
        int rk = (re ? (kh < 4 ? 1 : 2) : 0) * 3 + (ce ? (kw < 4 ? 1 : 2) : 0);
        if (rq != rk) val -= 100.0f;
      }
      v[j] = val;
    }
    ((f32x4*)Sadd)[(blk * 16 + f) * 64 + lane] = v;
  }
}

// ---------------- MFMA attention: block = (window, 4 heads), wave = head ----------
__global__ __launch_bounds__(256) void attn_mfma_kernel(
    const __hip_bfloat16* __restrict__ qkv,
    const float* __restrict__ Sadd,
    __hip_bfloat16* __restrict__ attn_out)
{
  __shared__ __align__(16) __hip_bfloat16 Pl[4][64 * 72];
  int blk = blockIdx.x;
  int win = blk >> 1, half = blk & 1;
  int w = threadIdx.x >> 6, l = threadIdx.x & 63;
  int head = half * 4 + w;
  int g = l >> 4, lm = l & 15;
  int wi = win & 63;
  int cls = (((wi >> 3) == 7) ? 2 : 0) | (((wi & 7) == 7) ? 1 : 0);
  const __hip_bfloat16* base = qkv + (size_t)win * 49 * 768 + head * 32;

  bf16x8 aQ[4], bK[4];
  #pragma unroll
  for (int mi = 0; mi < 4; ++mi) {
    int q = mi * 16 + lm; if (q > 48) q = 48;
    aQ[mi] = *(const bf16x8*)(base + q * 768 + g * 8);
  }
  #pragma unroll
  for (int ni = 0; ni < 4; ++ni) {
    int k = ni * 16 + lm; if (k > 48) k = 48;
    bK[ni] = *(const bf16x8*)(base + 256 + k * 768 + g * 8);
  }
  f32x4 acc[4][4] = {};
  #pragma unroll
  for (int mi = 0; mi < 4; ++mi)
    #pragma unroll
    for (int ni = 0; ni < 4; ++ni)
      acc[mi][ni] = __builtin_amdgcn_mfma_f32_16x16x32_bf16(aQ[mi], bK[ni], acc[mi][ni], 0, 0, 0);

  const float scale = 0.17677669529663687f;
  const f32x4* Sb = (const f32x4*)Sadd + (size_t)(cls * 8 + head) * 16 * 64 + l;

  f32x4 rsum[4];
  __hip_bfloat16* P = Pl[w];
  #pragma unroll
  for (int mi = 0; mi < 4; ++mi) {
    #pragma unroll
    for (int ni = 0; ni < 4; ++ni) {
      f32x4 sv = Sb[(mi * 4 + ni) * 64];
      #pragma unroll
      for (int j = 0; j < 4; ++j) acc[mi][ni][j] = acc[mi][ni][j] * scale + sv[j];
    }
    f32x4 mx = acc[mi][0];
    #pragma unroll
    for (int ni = 1; ni < 4; ++ni)
      #pragma unroll
      for (int j = 0; j < 4; ++j) mx[j] = fmaxf(mx[j], acc[mi][ni][j]);
    #pragma unroll
    for (int msk = 1; msk < 16; msk <<= 1)
      #pragma unroll
      for (int j = 0; j < 4; ++j) mx[j] = fmaxf(mx[j], __shfl_xor(mx[j], msk));
    f32x4 sm = {};
    #pragma unroll
    for (int ni = 0; ni < 4; ++ni)
      #pragma unroll
      for (int j = 0; j < 4; ++j) {
        float e = __expf(acc[mi][ni][j] - mx[j]);
        acc[mi][ni][j] = e;
        sm[j] += e;
      }
    #pragma unroll
    for (int msk = 1; msk < 16; msk <<= 1)
      #pragma unroll
      for (int j = 0; j < 4; ++j) sm[j] += __shfl_xor(sm[j], msk);
    rsum[mi] = sm;
    #pragma unroll
    for (int ni = 0; ni < 4; ++ni)
      #pragma unroll
      for (int j = 0; j < 4; ++j) {
        int q = mi * 16 + g * 4 + j;
        int key = ni * 16 + lm;
        P[q * 72 + key] = __float2bfloat16(acc[mi][ni][j]);
      }
  }

  bf16x8 bV[2][2];
  #pragma unroll
  for (int s = 0; s < 2; ++s)
    #pragma unroll
    for (int n2 = 0; n2 < 2; ++n2) {
      bf16x8 vv;
      #pragma unroll
      for (int e = 0; e < 8; ++e) {
        int key = s * 32 + g * 8 + e; if (key > 48) key = 48;
        vv[e] = __builtin_bit_cast(short, base[512 + key * 768 + n2 * 16 + lm]);
      }
      bV[s][n2] = vv;
    }

  f32x4 o[4][2] = {};
  #pragma unroll
  for (int s = 0; s < 2; ++s)
    #pragma unroll
    for (int mi2 = 0; mi2 < 4; ++mi2) {
      bf16x8 aP = *(const bf16x8*)&P[(mi2 * 16 + lm) * 72 + s * 32 + g * 8];
      #pragma unroll
      for (int n2 = 0; n2 < 2; ++n2)
        o[mi2][n2] = __builtin_amdgcn_mfma_f32_16x16x32_bf16(aP, bV[s][n2], o[mi2][n2], 0, 0, 0);
    }

  #pragma unroll
  for (int mi2 = 0; mi2 < 4; ++mi2) {
    f32x4 li;
    #pragma unroll
    for (int j = 0; j < 4; ++j) li[j] = 1.0f / rsum[mi2][j];
    #pragma unroll
    for (int n2 = 0; n2 < 2; ++n2)
      #pragma unroll
      for (int j = 0; j < 4; ++j) {
        int q = mi2 * 16 + g * 4 + j;
        if (q < 49)
          attn_out[((size_t)win * 49 + q) * 256 + head * 32 + n2 * 16 + lm] =
              __float2bfloat16(o[mi2][n2][j] * li[j]);
      }
  }
}

// ---------------- host launch ----------------
extern "C" void kernel_launch(void* const* d_in, const int* in_sizes, int n_in,
                              void* d_out, int out_size, void* d_ws, size_t ws_size,
                              hipStream_t stream) {
  const float* x          = (const float*)d_in[0];
  const float* g1         = (const float*)d_in[1];
  const float* b1         = (const float*)d_in[2];
  const float* qkv_w      = (const float*)d_in[3];
  const float* qkv_b      = (const float*)d_in[4];
  const float* bias_table = (const float*)d_in[5];
  const float* proj_w     = (const float*)d_in[6];
  const float* proj_b     = (const float*)d_in[7];
  const float* g2         = (const float*)d_in[8];
  const float* b2         = (const float*)d_in[9];
  const float* w1         = (const float*)d_in[10];
  const float* bm1        = (const float*)d_in[11];
  const float* w2         = (const float*)d_in[12];
  const float* bm2        = (const float*)d_in[13];
  float* out = (float*)d_out;

  char* ws = (char*)d_ws;
  __hip_bfloat16* A_ln   = (__hip_bfloat16*)(ws);
  __hip_bfloat16* qkvb   = (__hip_bfloat16*)(ws + 51380224);
  __hip_bfloat16* attn_o = (__hip_bfloat16*)(ws + 205520896);
  __hip_bfloat16* hidden = qkvb;
  __hip_bfloat16* qkv_wb  = (__hip_bfloat16*)(ws + 256901120);
  __hip_bfloat16* proj_wb = qkv_wb + 196608;
  __hip_bfloat16* w1b     = proj_wb + 65536;
  __hip_bfloat16* w2b     = w1b + 262144;
  float* Sadd = (float*)(ws + 258473984);

  cvt_kernel<<<(196608 + 255) / 256, 256, 0, stream>>>(qkv_w, qkv_wb, 196608);
  cvt_kernel<<<(65536  + 255) / 256, 256, 0, stream>>>(proj_w, proj_wb, 65536);
  cvt_kernel<<<(262144 + 255) / 256, 256, 0, stream>>>(w1, w1b, 262144);
  cvt_kernel<<<(262144 + 255) / 256, 256, 0, stream>>>(w2, w2b, 262144);
  bias_prep_kernel<<<32, 256, 0, stream>>>(bias_table, Sadd);

  ln_kernel<true><<<MROWS / 4, 256, 0, stream>>>(x, g1, b1, A_ln);

  strip3<EPI_QKV, 256><<<256, 512, 0, stream>>>(
      A_ln, qkv_wb, 6, qkv_b, nullptr, nullptr, qkvb);

  attn_mfma_kernel<<<4096, 256, 0, stream>>>(qkvb, Sadd, attn_o);

  strip3<EPI_PROJ, 256><<<256, 512, 0, stream>>>(
      attn_o, proj_wb, 2, proj_b, x, out, nullptr);

  ln_kernel<false><<<MROWS / 4, 256, 0, stream>>>(out, g2, b2, A_ln);

  strip3<EPI_MLP1, 256><<<256, 512, 0, stream>>>(
      A_ln, w1b, 8, bm1, nullptr, nullptr, hidden);

  strip3<EPI_MLP2, 1024><<<256, 512, 0, stream>>>(
      hidden, w2b, 2, bm2, nullptr, out, nullptr);
}